// Round 8
// baseline (1071.356 us; speedup 1.0000x reference)
//
#include <hip/hip_runtime.h>
#include <hip/hip_fp16.h>

#define NN   100000
#define NE   1600000
#define NBUCK 391                 // ceil(NN/256) buckets of 256 nodes
#define NW1   512                 // pass-1 workgroups
#define CH1   (NE / NW1)          // 3125 edges per wg
#define GN    (NBUCK * NW1)       // 200192 scan entries
#define SC    512
#define SNB   (GN / SC)           // 391 scan blocks
#define SLN   ((size_t)NN * 16)   // elements per 16-feat slice
constexpr float EPSV = 1e-5f;

typedef _Float16 f16x8 __attribute__((ext_vector_type(8)));
typedef float    f32x4 __attribute__((ext_vector_type(4)));

// ---------------- graph prep: 2-level bucket CSR build ----------------

__global__ __launch_bounds__(256) void p1hist_kernel(const int* __restrict__ dst,
                                                     int* __restrict__ G) {
    __shared__ int h[NBUCK];
    int t = threadIdx.x, wg = blockIdx.x;
    for (int i = t; i < NBUCK; i += 256) h[i] = 0;
    __syncthreads();
    int base = wg * CH1;
    for (int e = base + t; e < base + CH1; e += 256)
        atomicAdd(&h[dst[e] >> 8], 1);
    __syncthreads();
    for (int i = t; i < NBUCK; i += 256) G[i * NW1 + wg] = h[i];
}

__global__ __launch_bounds__(256) void gscan1_kernel(const int* __restrict__ G,
                                                     int* __restrict__ bsum) {
    __shared__ int red[256];
    int t = threadIdx.x;
    int base = blockIdx.x * SC + t * 2;
    red[t] = G[base] + G[base + 1];
    __syncthreads();
    #pragma unroll
    for (int off = 128; off > 0; off >>= 1) {
        if (t < off) red[t] += red[t + off];
        __syncthreads();
    }
    if (t == 0) bsum[blockIdx.x] = red[0];
}

__global__ __launch_bounds__(512) void gscan2_kernel(const int* __restrict__ bsum,
                                                     int* __restrict__ boff) {
    __shared__ int s[512];
    int t = threadIdx.x;
    int v = (t < SNB) ? bsum[t] : 0;
    s[t] = v;
    __syncthreads();
    #pragma unroll
    for (int off = 1; off < 512; off <<= 1) {
        int u = (t >= off) ? s[t - off] : 0;
        __syncthreads();
        s[t] += u;
        __syncthreads();
    }
    if (t < SNB) boff[t] = s[t] - v;   // exclusive
}

__global__ __launch_bounds__(256) void gscan3_kernel(int* __restrict__ G,
                                                     const int* __restrict__ boff) {
    __shared__ int s[256];
    int t = threadIdx.x;
    int base = blockIdx.x * SC + t * 2;
    int c0 = G[base], c1 = G[base + 1];
    int pair = c0 + c1;
    s[t] = pair;
    __syncthreads();
    #pragma unroll
    for (int off = 1; off < 256; off <<= 1) {
        int u = (t >= off) ? s[t - off] : 0;
        __syncthreads();
        s[t] += u;
        __syncthreads();
    }
    int excl = boff[blockIdx.x] + s[t] - pair;
    G[base]     = excl;
    G[base + 1] = excl + c0;
}

__global__ __launch_bounds__(256) void p1fill_kernel(const int* __restrict__ src,
                                                     const int* __restrict__ dst,
                                                     const int* __restrict__ G,
                                                     int* __restrict__ ebuf) {
    __shared__ int cur[NBUCK];
    int t = threadIdx.x, wg = blockIdx.x;
    for (int i = t; i < NBUCK; i += 256) cur[i] = G[i * NW1 + wg];
    __syncthreads();
    int base = wg * CH1;
    for (int e = base + t; e < base + CH1; e += 256) {
        int d = dst[e];
        int pos = atomicAdd(&cur[d >> 8], 1);
        ebuf[pos] = src[e] | ((d & 255) << 17);
    }
}

__global__ __launch_bounds__(256) void p2build_kernel(const int* __restrict__ ebuf,
                                                      const int* __restrict__ G,
                                                      int* __restrict__ rowptr,
                                                      int* __restrict__ srcsorted,
                                                      float* __restrict__ dinv) {
    __shared__ int cnt[256];
    __shared__ int s[256];
    __shared__ int cur[256];
    int t = threadIdx.x, b = blockIdx.x;
    int base = G[b * NW1];
    int endp = (b == NBUCK - 1) ? NE : G[(b + 1) * NW1];
    cnt[t] = 0;
    __syncthreads();
    for (int e = base + t; e < endp; e += 256)
        atomicAdd(&cnt[ebuf[e] >> 17], 1);
    __syncthreads();
    int c = cnt[t];
    s[t] = c;
    __syncthreads();
    #pragma unroll
    for (int off = 1; off < 256; off <<= 1) {
        int u = (t >= off) ? s[t - off] : 0;
        __syncthreads();
        s[t] += u;
        __syncthreads();
    }
    int excl = s[t] - c;
    int node = b * 256 + t;
    if (node < NN) {
        rowptr[node] = base + excl;
        dinv[node]   = rsqrtf((float)c + 1.0f);
    }
    cur[t] = base + excl;
    __syncthreads();
    for (int e = base + t; e < endp; e += 256) {
        int p = ebuf[e];
        int pos = atomicAdd(&cur[p >> 17], 1);
        srcsorted[pos] = p & 0x1FFFF;
    }
    if (b == NBUCK - 1 && t == 0) rowptr[NN] = NE;
}

// ---------------- weight prep: W[k][n] fp32 -> Wt[n][k] fp16 ----------------

__global__ void wprep_kernel(const float* __restrict__ W1, const float* __restrict__ W2,
                             __half* __restrict__ Wt) {
    int b = blockIdx.x;
    int layer = b >> 7, n = b & 127, k = threadIdx.x;
    const float* W = layer ? W2 : W1;
    Wt[layer * 16384 + n * 128 + k] = __float2half_rn(W[k * 128 + n]);
}

// ---------------- batchnorm (separate pass over slice-major fp16 B) ----------------

__global__ __launch_bounds__(256) void bnstats_kernel(const __half* __restrict__ X,
                                                      float* __restrict__ stats) {
    int f2 = threadIdx.x & 63;          // half2 column (feats 2f2, 2f2+1)
    int rg = threadIdx.x >> 6;          // 0..3
    int sl = f2 >> 3, off = f2 & 7;
    const __half2* base = (const __half2*)(X + (size_t)sl * SLN) + off;
    float s0 = 0.f, s1 = 0.f, q0 = 0.f, q1 = 0.f;
    for (int r = blockIdx.x * 4 + rg; r < NN; r += gridDim.x * 4) {
        float2 v = __half22float2(base[(size_t)r * 8]);
        s0 += v.x; s1 += v.y; q0 += v.x * v.x; q1 += v.y * v.y;
    }
    int c = f2 * 2;
    atomicAdd(&stats[c],       s0);
    atomicAdd(&stats[c + 1],   s1);
    atomicAdd(&stats[128 + c],     q0);
    atomicAdd(&stats[128 + c + 1], q1);
}

__global__ void bnfinal_kernel(const float* __restrict__ st, const float* __restrict__ g,
                               const float* __restrict__ be, float* __restrict__ sc) {
    int f = threadIdx.x;
    float mu  = st[f] * (1.0f / NN);
    float var = st[128 + f] * (1.0f / NN) - mu * mu;
    float rstd = rsqrtf(var + EPSV);
    float scale = g[f] * rstd;
    sc[f]       = scale;
    sc[128 + f] = be[f] - mu * scale;
}

// ---------------- MFMA fp16 GEMM: 64 nodes x 128 feats, K=128 ----------------
// LDS XOR-swizzle both sides: byte = row*256 + (colByte ^ ((row&7)<<4))

__device__ __forceinline__ int swzb(int row, int colByte) {
    return row * 256 + (colByte ^ ((row & 7) << 4));
}

// TIN=float: row-major fp32 input. TIN=__half: slice-major fp16 input.
template<bool BN, typename TIN>
__global__ __launch_bounds__(256) void gemm128m_kernel(const TIN* __restrict__ X,
        const __half* __restrict__ Wt, const float* __restrict__ sc,
        const float* __restrict__ dinv, __half* __restrict__ Y) {
    __shared__ __align__(16) char Xs[64 * 256];
    __shared__ __align__(16) char Wts[128 * 256];
    __shared__ float dvs[64];
    int tid = threadIdx.x;
    int node0 = blockIdx.x * 64;

    {   // stage Wt
        int n = tid >> 1, c0 = (tid & 1) * 64;
        const _Float16* g = (const _Float16*)Wt + n * 128 + c0;
        #pragma unroll
        for (int j = 0; j < 8; ++j) {
            f16x8 v = *(const f16x8*)(g + j * 8);
            *(f16x8*)(Wts + swzb(n, (c0 + j * 8) * 2)) = v;
        }
    }
    {   // stage X (+BN+ReLU), cvt fp16
        int r = tid >> 2, c0 = (tid & 3) * 32;
        int grow = node0 + r;
        #pragma unroll
        for (int j = 0; j < 4; ++j) {
            int c = c0 + j * 8;
            f16x8 o;
            if (grow < NN) {
                float f[8];
                if constexpr (sizeof(TIN) == 4) {
                    float4 u0 = *(const float4*)((const float*)X + (size_t)grow * 128 + c);
                    float4 u1 = *(const float4*)((const float*)X + (size_t)grow * 128 + c + 4);
                    f[0] = u0.x; f[1] = u0.y; f[2] = u0.z; f[3] = u0.w;
                    f[4] = u1.x; f[5] = u1.y; f[6] = u1.z; f[7] = u1.w;
                } else {
                    const _Float16* sp = (const _Float16*)X + (size_t)(c >> 4) * SLN
                                         + (size_t)grow * 16 + (c & 15);
                    f16x8 h = *(const f16x8*)sp;
                    #pragma unroll
                    for (int i = 0; i < 8; ++i) f[i] = (float)h[i];
                }
                #pragma unroll
                for (int i = 0; i < 8; ++i) {
                    if constexpr (BN) f[i] = fmaxf(fmaf(f[i], sc[c + i], sc[128 + c + i]), 0.f);
                    o[i] = (_Float16)f[i];
                }
            } else {
                #pragma unroll
                for (int i = 0; i < 8; ++i) o[i] = (_Float16)0.f;
            }
            *(f16x8*)(Xs + swzb(r, c * 2)) = o;
        }
    }
    if (tid < 64) dvs[tid] = (node0 + tid < NN) ? dinv[node0 + tid] : 0.f;
    __syncthreads();

    int lane = tid & 63;
    int wv   = tid >> 6;
    int n0w  = wv * 32;
    int lm   = lane & 15;
    int lg   = lane >> 4;

    f32x4 acc[4][2] = {};
    #pragma unroll
    for (int s = 0; s < 4; ++s) {
        int kb = (s * 32 + lg * 8) * 2;
        f16x8 a[4], b[2];
        #pragma unroll
        for (int i = 0; i < 4; ++i)
            a[i] = *(const f16x8*)(Xs + swzb(i * 16 + lm, kb));
        #pragma unroll
        for (int r = 0; r < 2; ++r)
            b[r] = *(const f16x8*)(Wts + swzb(n0w + r * 16 + lm, kb));
        #pragma unroll
        for (int i = 0; i < 4; ++i)
            #pragma unroll
            for (int r = 0; r < 2; ++r)
                acc[i][r] = __builtin_amdgcn_mfma_f32_16x16x32_f16(a[i], b[r], acc[i][r], 0, 0, 0);
    }

    // slice-major epilogue: feat n -> Y + (n>>4)*SLN + row*16 + (n&15)
    _Float16* Y0 = (_Float16*)Y + (size_t)(n0w >> 4) * SLN;
    _Float16* Y1 = (_Float16*)Y + (size_t)((n0w >> 4) + 1) * SLN;
    #pragma unroll
    for (int i = 0; i < 4; ++i) {
        #pragma unroll
        for (int q = 0; q < 4; ++q) {
            int row = i * 16 + lg * 4 + q;
            int grow = node0 + row;
            if (grow < NN) {
                float di = dvs[row];
                Y0[(size_t)grow * 16 + lm] = (_Float16)(acc[i][0][q] * di);
                Y1[(size_t)grow * 16 + lm] = (_Float16)(acc[i][1][q] * di);
            }
        }
    }
}

// ---------------- final dense GEMM 128->40 (fp32 VALU, sliced fp16 in) ----------------

__global__ __launch_bounds__(256) void gemm40_kernel(const __half* __restrict__ X,
        const float* __restrict__ W, const float* __restrict__ sc,
        const float* __restrict__ dinv, __half* __restrict__ Y) {
    __shared__ float Ws[128][40];
    __shared__ float Xs[32][132];
    int tx = threadIdx.x, ty = threadIdx.y;
    int tid = ty * 8 + tx;
    int node0 = blockIdx.x * 32;

    float* wf = &Ws[0][0];
    for (int idx = tid; idx < 128 * 40; idx += 256) wf[idx] = W[idx];
    for (int idx = tid * 8; idx < 32 * 128; idx += 256 * 8) {
        int n = idx >> 7, f = idx & 127;
        const _Float16* sp = (const _Float16*)X + (size_t)(f >> 4) * SLN
                             + (size_t)(node0 + n) * 16 + (f & 15);
        f16x8 h = *(const f16x8*)sp;
        float v[8];
        #pragma unroll
        for (int i = 0; i < 8; ++i)
            v[i] = fmaxf(fmaf((float)h[i], sc[f + i], sc[128 + f + i]), 0.f);
        *(float4*)&Xs[n][f]     = make_float4(v[0], v[1], v[2], v[3]);
        *(float4*)&Xs[n][f + 4] = make_float4(v[4], v[5], v[6], v[7]);
    }
    __syncthreads();

    float acc[5] = {0, 0, 0, 0, 0};
    int f0 = tx * 5;
    #pragma unroll 4
    for (int k = 0; k < 128; ++k) {
        float xv = Xs[ty][k];
        #pragma unroll
        for (int j = 0; j < 5; ++j) acc[j] = fmaf(xv, Ws[k][f0 + j], acc[j]);
    }
    float di = dinv[node0 + ty];
    __half* yp = Y + (size_t)(node0 + ty) * 40 + f0;
    #pragma unroll
    for (int j = 0; j < 5; ++j) yp[j] = __float2half_rn(acc[j] * di);
}

// ---------------- feature-sliced XCD-pinned aggregation ----------------
// grid = 8 slices x (NN/4) chunks; slice = bid&7 -> pins to one XCD (round-robin);
// each XCD's gather working set = one 3.2MB slice -> L2-resident.
__global__ __launch_bounds__(256) void agg128s_kernel(const __half* __restrict__ H,
        const int* __restrict__ rowptr, const int* __restrict__ srcs,
        const float* __restrict__ dinv, const float* __restrict__ bias,
        __half* __restrict__ Bout) {
    int bid = blockIdx.x;
    int slice = bid & 7;
    int chunk = bid >> 3;
    int wave = threadIdx.x >> 6, lane = threadIdx.x & 63;
    int node = chunk * 4 + wave;
    int g  = lane >> 3;          // edge group 0..7
    int fl = lane & 7;           // half2 index within slice
    const __half2* Hs = (const __half2*)(H + (size_t)slice * SLN) + fl;
    int beg = rowptr[node], end = rowptr[node + 1];
    float a0 = 0.f, a1 = 0.f;
    for (int e = beg + g; e < end; e += 8) {
        int s = srcs[e];
        float2 v = __half22float2(Hs[(size_t)s * 8]);
        a0 += v.x; a1 += v.y;
    }
    a0 += __shfl_xor(a0, 8);  a1 += __shfl_xor(a1, 8);
    a0 += __shfl_xor(a0, 16); a1 += __shfl_xor(a1, 16);
    a0 += __shfl_xor(a0, 32); a1 += __shfl_xor(a1, 32);
    float di = dinv[node];
    float2 hs = __half22float2(Hs[(size_t)node * 8]);
    int c = slice * 16 + fl * 2;
    a0 = di * (a0 + hs.x) + bias[c];
    a1 = di * (a1 + hs.y) + bias[c + 1];
    if (g == 0) {
        __half2 hv;
        hv.x = __float2half_rn(a0); hv.y = __float2half_rn(a1);
        *((__half2*)(Bout + (size_t)slice * SLN + (size_t)node * 16) + fl) = hv;
    }
}

__global__ __launch_bounds__(256) void agg40_softmax_kernel(const __half* __restrict__ H,
        const int* __restrict__ rowptr, const int* __restrict__ srcs,
        const float* __restrict__ dinv, const float* __restrict__ bias,
        float* __restrict__ out) {
    int wave = threadIdx.x >> 6;
    int lane = threadIdx.x & 63;
    int node = blockIdx.x * 4 + wave;
    int beg = rowptr[node], end = rowptr[node + 1];
    bool act = lane < 40;
    int ln = act ? lane : 0;
    float a0 = 0.f, a1 = 0.f, a2 = 0.f, a3 = 0.f;
    int e = beg;
    for (; e + 3 < end; e += 4) {
        int s0 = srcs[e], s1 = srcs[e + 1], s2 = srcs[e + 2], s3 = srcs[e + 3];
        a0 += __half2float(H[(size_t)s0 * 40 + ln]);
        a1 += __half2float(H[(size_t)s1 * 40 + ln]);
        a2 += __half2float(H[(size_t)s2 * 40 + ln]);
        a3 += __half2float(H[(size_t)s3 * 40 + ln]);
    }
    for (; e < end; ++e) a0 += __half2float(H[(size_t)srcs[e] * 40 + ln]);
    float di = dinv[node];
    float hs = __half2float(H[(size_t)node * 40 + ln]);
    float v = act ? (di * (a0 + a1 + a2 + a3 + hs) + bias[ln]) : -3.0e38f;
    float m = v;
    #pragma unroll
    for (int off = 32; off > 0; off >>= 1) m = fmaxf(m, __shfl_xor(m, off));
    float ev = act ? expf(v - m) : 0.f;
    float ssum = ev;
    #pragma unroll
    for (int off = 32; off > 0; off >>= 1) ssum += __shfl_xor(ssum, off);
    if (act) out[(size_t)node * 40 + lane] = ev / ssum;
}

// ---------------- launch ----------------

extern "C" void kernel_launch(void* const* d_in, const int* in_sizes, int n_in,
                              void* d_out, int out_size, void* d_ws, size_t ws_size,
                              hipStream_t stream) {
    const float* x   = (const float*)d_in[0];
    const int*   ei  = (const int*)d_in[1];
    const float* W1  = (const float*)d_in[2];
    const float* b1  = (const float*)d_in[3];
    const float* g1  = (const float*)d_in[4];
    const float* be1 = (const float*)d_in[5];
    const float* W2  = (const float*)d_in[6];
    const float* b2  = (const float*)d_in[7];
    const float* g2  = (const float*)d_in[8];
    const float* be2 = (const float*)d_in[9];
    const float* W3  = (const float*)d_in[10];
    const float* b3  = (const float*)d_in[11];
    float* out = (float*)d_out;
    const int* src = ei;
    const int* dst = ei + NE;

    char* p = (char*)d_ws;
    auto alloc = [&](size_t bytes) { char* r = p; p += (bytes + 255) & ~255ull; return r; };
    int*    rowptr    = (int*)   alloc((size_t)(NN + 1) * 4);
    int*    srcsorted = (int*)   alloc((size_t)NE * 4);
    float*  dinv      = (float*) alloc((size_t)NN * 4);
    float*  sc        = (float*) alloc(256 * 4);
    int*    G         = (int*)   alloc((size_t)GN * 4);
    int*    bsum      = (int*)   alloc((size_t)SNB * 4);
    int*    boff      = (int*)   alloc((size_t)SNB * 4);
    float*  stats2    = (float*) alloc(512 * 4);
    __half* Wth       = (__half*)alloc((size_t)2 * 16384 * 2);
    __half* A         = (__half*)alloc((size_t)NN * 128 * 2);   // slice-major
    __half* Bh        = (__half*)alloc((size_t)NN * 128 * 2);   // slice-major
    int*    ebuf      = (int*)A;

    // prep
    wprep_kernel<<<256, 128, 0, stream>>>(W1, W2, Wth);
    p1hist_kernel<<<NW1, 256, 0, stream>>>(dst, G);
    gscan1_kernel<<<SNB, 256, 0, stream>>>(G, bsum);
    gscan2_kernel<<<1, 512, 0, stream>>>(bsum, boff);
    gscan3_kernel<<<SNB, 256, 0, stream>>>(G, boff);
    p1fill_kernel<<<NW1, 256, 0, stream>>>(src, dst, G, ebuf);
    p2build_kernel<<<NBUCK, 256, 0, stream>>>(ebuf, G, rowptr, srcsorted, dinv);
    hipMemsetAsync(stats2, 0, 512 * 4, stream);

    const int GB  = (NN + 63) / 64;    // 1563
    const int GAG = (NN / 4) * 8;      // 200000 sliced agg blocks
    // layer 1
    gemm128m_kernel<false, float><<<GB, 256, 0, stream>>>(x, Wth, nullptr, dinv, A);
    agg128s_kernel<<<GAG, 256, 0, stream>>>(A, rowptr, srcsorted, dinv, b1, Bh);
    bnstats_kernel<<<1024, 256, 0, stream>>>(Bh, stats2);
    bnfinal_kernel<<<1, 128, 0, stream>>>(stats2, g1, be1, sc);
    // layer 2
    gemm128m_kernel<true, __half><<<GB, 256, 0, stream>>>(Bh, Wth + 16384, sc, dinv, A);
    agg128s_kernel<<<GAG, 256, 0, stream>>>(A, rowptr, srcsorted, dinv, b2, Bh);
    bnstats_kernel<<<1024, 256, 0, stream>>>(Bh, stats2 + 256);
    bnfinal_kernel<<<1, 128, 0, stream>>>(stats2 + 256, g2, be2, sc);
    // layer 3
    gemm40_kernel<<<NN / 32, dim3(8, 32), 0, stream>>>(Bh, W3, sc, dinv, A);
    agg40_softmax_kernel<<<NN / 4, 256, 0, stream>>>(A, rowptr, srcsorted, dinv, b3, out);
}

// Round 9
// 777.614 us; speedup vs baseline: 1.3777x; 1.3777x over previous
//
#include <hip/hip_runtime.h>
#include <hip/hip_fp16.h>

#define NN   100000
#define NE   1600000
#define NBUCK 391                 // ceil(NN/256) buckets of 256 nodes
#define NW1   512                 // pass-1 workgroups
#define CH1   (NE / NW1)          // 3125 edges per wg
#define GN    (NBUCK * NW1)       // 200192 scan entries
#define SC    512
#define SNB   (GN / SC)           // 391 scan blocks
constexpr float EPSV = 1e-5f;

typedef _Float16 f16x8 __attribute__((ext_vector_type(8)));
typedef float    f32x4 __attribute__((ext_vector_type(4)));

// ---------------- graph prep: 2-level bucket CSR build ----------------

__global__ __launch_bounds__(256) void p1hist_kernel(const int* __restrict__ dst,
                                                     int* __restrict__ G) {
    __shared__ int h[NBUCK];
    int t = threadIdx.x, wg = blockIdx.x;
    for (int i = t; i < NBUCK; i += 256) h[i] = 0;
    __syncthreads();
    int base = wg * CH1;
    for (int e = base + t; e < base + CH1; e += 256)
        atomicAdd(&h[dst[e] >> 8], 1);
    __syncthreads();
    for (int i = t; i < NBUCK; i += 256) G[i * NW1 + wg] = h[i];
}

__global__ __launch_bounds__(256) void gscan1_kernel(const int* __restrict__ G,
                                                     int* __restrict__ bsum) {
    __shared__ int red[256];
    int t = threadIdx.x;
    int base = blockIdx.x * SC + t * 2;
    red[t] = G[base] + G[base + 1];
    __syncthreads();
    #pragma unroll
    for (int off = 128; off > 0; off >>= 1) {
        if (t < off) red[t] += red[t + off];
        __syncthreads();
    }
    if (t == 0) bsum[blockIdx.x] = red[0];
}

__global__ __launch_bounds__(512) void gscan2_kernel(const int* __restrict__ bsum,
                                                     int* __restrict__ boff) {
    __shared__ int s[512];
    int t = threadIdx.x;
    int v = (t < SNB) ? bsum[t] : 0;
    s[t] = v;
    __syncthreads();
    #pragma unroll
    for (int off = 1; off < 512; off <<= 1) {
        int u = (t >= off) ? s[t - off] : 0;
        __syncthreads();
        s[t] += u;
        __syncthreads();
    }
    if (t < SNB) boff[t] = s[t] - v;   // exclusive
}

__global__ __launch_bounds__(256) void gscan3_kernel(int* __restrict__ G,
                                                     const int* __restrict__ boff) {
    __shared__ int s[256];
    int t = threadIdx.x;
    int base = blockIdx.x * SC + t * 2;
    int c0 = G[base], c1 = G[base + 1];
    int pair = c0 + c1;
    s[t] = pair;
    __syncthreads();
    #pragma unroll
    for (int off = 1; off < 256; off <<= 1) {
        int u = (t >= off) ? s[t - off] : 0;
        __syncthreads();
        s[t] += u;
        __syncthreads();
    }
    int excl = boff[blockIdx.x] + s[t] - pair;
    G[base]     = excl;
    G[base + 1] = excl + c0;
}

__global__ __launch_bounds__(256) void p1fill_kernel(const int* __restrict__ src,
                                                     const int* __restrict__ dst,
                                                     const int* __restrict__ G,
                                                     int* __restrict__ ebuf) {
    __shared__ int cur[NBUCK];
    int t = threadIdx.x, wg = blockIdx.x;
    for (int i = t; i < NBUCK; i += 256) cur[i] = G[i * NW1 + wg];
    __syncthreads();
    int base = wg * CH1;
    for (int e = base + t; e < base + CH1; e += 256) {
        int d = dst[e];
        int pos = atomicAdd(&cur[d >> 8], 1);
        ebuf[pos] = src[e] | ((d & 255) << 17);
    }
}

__global__ __launch_bounds__(256) void p2build_kernel(const int* __restrict__ ebuf,
                                                      const int* __restrict__ G,
                                                      int* __restrict__ rowptr,
                                                      int* __restrict__ srcsorted,
                                                      float* __restrict__ dinv) {
    __shared__ int cnt[256];
    __shared__ int s[256];
    __shared__ int cur[256];
    int t = threadIdx.x, b = blockIdx.x;
    int base = G[b * NW1];
    int endp = (b == NBUCK - 1) ? NE : G[(b + 1) * NW1];
    cnt[t] = 0;
    __syncthreads();
    for (int e = base + t; e < endp; e += 256)
        atomicAdd(&cnt[ebuf[e] >> 17], 1);
    __syncthreads();
    int c = cnt[t];
    s[t] = c;
    __syncthreads();
    #pragma unroll
    for (int off = 1; off < 256; off <<= 1) {
        int u = (t >= off) ? s[t - off] : 0;
        __syncthreads();
        s[t] += u;
        __syncthreads();
    }
    int excl = s[t] - c;
    int node = b * 256 + t;
    if (node < NN) {
        rowptr[node] = base + excl;
        dinv[node]   = rsqrtf((float)c + 1.0f);
    }
    cur[t] = base + excl;
    __syncthreads();
    for (int e = base + t; e < endp; e += 256) {
        int p = ebuf[e];
        int pos = atomicAdd(&cur[p >> 17], 1);
        srcsorted[pos] = p & 0x1FFFF;
    }
    if (b == NBUCK - 1 && t == 0) rowptr[NN] = NE;
}

// ---------------- weight prep: W[k][n] fp32 -> Wt[n][k] fp16 ----------------

__global__ void wprep_kernel(const float* __restrict__ W1, const float* __restrict__ W2,
                             __half* __restrict__ Wt) {
    int b = blockIdx.x;
    int layer = b >> 7, n = b & 127, k = threadIdx.x;
    const float* W = layer ? W2 : W1;
    Wt[layer * 16384 + n * 128 + k] = __float2half_rn(W[k * 128 + n]);
}

// ---------------- batchnorm stats (streaming pass over row-major fp16 B) --------

__global__ __launch_bounds__(256) void bnstats_kernel(const __half* __restrict__ X,
                                                      float* __restrict__ stats) {
    int f2 = threadIdx.x & 63;          // half2 col: feats 2f2, 2f2+1
    int rg = threadIdx.x >> 6;          // 0..3
    const __half2* base = (const __half2*)X + f2;
    float s0 = 0.f, s1 = 0.f, q0 = 0.f, q1 = 0.f;
    for (int r = blockIdx.x * 4 + rg; r < NN; r += gridDim.x * 4) {
        float2 v = __half22float2(base[(size_t)r * 64]);
        s0 += v.x; s1 += v.y; q0 += v.x * v.x; q1 += v.y * v.y;
    }
    int c = f2 * 2;
    atomicAdd(&stats[c],           s0);
    atomicAdd(&stats[c + 1],       s1);
    atomicAdd(&stats[128 + c],     q0);
    atomicAdd(&stats[128 + c + 1], q1);
}

__global__ void bnfinal_kernel(const float* __restrict__ st, const float* __restrict__ g,
                               const float* __restrict__ be, float* __restrict__ sc) {
    int f = threadIdx.x;
    float mu  = st[f] * (1.0f / NN);
    float var = st[128 + f] * (1.0f / NN) - mu * mu;
    float rstd = rsqrtf(var + EPSV);
    float scale = g[f] * rstd;
    sc[f]       = scale;
    sc[128 + f] = be[f] - mu * scale;
}

// ---------------- MFMA fp16 GEMM: 64 nodes x 128 feats, K=128 ----------------
// LDS XOR-swizzle both sides: byte = row*256 + (colByte ^ ((row&7)<<4))

__device__ __forceinline__ int swzb(int row, int colByte) {
    return row * 256 + (colByte ^ ((row & 7) << 4));
}

template<bool BN, typename TIN>
__global__ __launch_bounds__(256) void gemm128m_kernel(const TIN* __restrict__ X,
        const __half* __restrict__ Wt, const float* __restrict__ sc,
        const float* __restrict__ dinv, __half* __restrict__ Y) {
    __shared__ __align__(16) char Xs[64 * 256];
    __shared__ __align__(16) char Wts[128 * 256];
    __shared__ float dvs[64];
    int tid = threadIdx.x;
    int node0 = blockIdx.x * 64;

    {   // stage Wt (pre-transposed fp16)
        int n = tid >> 1, c0 = (tid & 1) * 64;
        const _Float16* g = (const _Float16*)Wt + n * 128 + c0;
        #pragma unroll
        for (int j = 0; j < 8; ++j) {
            f16x8 v = *(const f16x8*)(g + j * 8);
            *(f16x8*)(Wts + swzb(n, (c0 + j * 8) * 2)) = v;
        }
    }
    {   // stage X (+BN+ReLU), cvt fp16
        int r = tid >> 2, c0 = (tid & 3) * 32;
        int grow = node0 + r;
        #pragma unroll
        for (int j = 0; j < 4; ++j) {
            int c = c0 + j * 8;
            f16x8 o;
            if (grow < NN) {
                float f[8];
                if constexpr (sizeof(TIN) == 4) {
                    float4 u0 = *(const float4*)((const float*)X + (size_t)grow * 128 + c);
                    float4 u1 = *(const float4*)((const float*)X + (size_t)grow * 128 + c + 4);
                    f[0] = u0.x; f[1] = u0.y; f[2] = u0.z; f[3] = u0.w;
                    f[4] = u1.x; f[5] = u1.y; f[6] = u1.z; f[7] = u1.w;
                } else {
                    f16x8 h = *(const f16x8*)((const _Float16*)X + (size_t)grow * 128 + c);
                    #pragma unroll
                    for (int i = 0; i < 8; ++i) f[i] = (float)h[i];
                }
                #pragma unroll
                for (int i = 0; i < 8; ++i) {
                    if constexpr (BN) f[i] = fmaxf(fmaf(f[i], sc[c + i], sc[128 + c + i]), 0.f);
                    o[i] = (_Float16)f[i];
                }
            } else {
                #pragma unroll
                for (int i = 0; i < 8; ++i) o[i] = (_Float16)0.f;
            }
            *(f16x8*)(Xs + swzb(r, c * 2)) = o;
        }
    }
    if (tid < 64) dvs[tid] = (node0 + tid < NN) ? dinv[node0 + tid] : 0.f;
    __syncthreads();

    int lane = tid & 63;
    int wv   = tid >> 6;
    int n0w  = wv * 32;
    int lm   = lane & 15;
    int lg   = lane >> 4;

    f32x4 acc[4][2] = {};
    #pragma unroll
    for (int s = 0; s < 4; ++s) {
        int kb = (s * 32 + lg * 8) * 2;
        f16x8 a[4], b[2];
        #pragma unroll
        for (int i = 0; i < 4; ++i)
            a[i] = *(const f16x8*)(Xs + swzb(i * 16 + lm, kb));
        #pragma unroll
        for (int r = 0; r < 2; ++r)
            b[r] = *(const f16x8*)(Wts + swzb(n0w + r * 16 + lm, kb));
        #pragma unroll
        for (int i = 0; i < 4; ++i)
            #pragma unroll
            for (int r = 0; r < 2; ++r)
                acc[i][r] = __builtin_amdgcn_mfma_f32_16x16x32_f16(a[i], b[r], acc[i][r], 0, 0, 0);
    }

    _Float16* Yh = (_Float16*)Y;
    #pragma unroll
    for (int i = 0; i < 4; ++i) {
        #pragma unroll
        for (int q = 0; q < 4; ++q) {
            int row = i * 16 + lg * 4 + q;
            int grow = node0 + row;
            if (grow < NN) {
                float di = dvs[row];
                Yh[(size_t)grow * 128 + n0w + lm]      = (_Float16)(acc[i][0][q] * di);
                Yh[(size_t)grow * 128 + n0w + 16 + lm] = (_Float16)(acc[i][1][q] * di);
            }
        }
    }
}

// ---------------- final dense GEMM 128->40 (fp32 VALU, fp16 in) ----------------

__global__ __launch_bounds__(256) void gemm40_kernel(const __half* __restrict__ X,
        const float* __restrict__ W, const float* __restrict__ sc,
        const float* __restrict__ dinv, __half* __restrict__ Y) {
    __shared__ float Ws[128][40];
    __shared__ float Xs[32][132];
    int tx = threadIdx.x, ty = threadIdx.y;
    int tid = ty * 8 + tx;
    int node0 = blockIdx.x * 32;

    float* wf = &Ws[0][0];
    for (int idx = tid; idx < 128 * 40; idx += 256) wf[idx] = W[idx];
    for (int idx = tid * 8; idx < 32 * 128; idx += 256 * 8) {
        int n = idx >> 7, f = idx & 127;
        f16x8 h = *(const f16x8*)((const _Float16*)X + (size_t)(node0 + n) * 128 + f);
        float v[8];
        #pragma unroll
        for (int i = 0; i < 8; ++i)
            v[i] = fmaxf(fmaf((float)h[i], sc[f + i], sc[128 + f + i]), 0.f);
        *(float4*)&Xs[n][f]     = make_float4(v[0], v[1], v[2], v[3]);
        *(float4*)&Xs[n][f + 4] = make_float4(v[4], v[5], v[6], v[7]);
    }
    __syncthreads();

    float acc[5] = {0, 0, 0, 0, 0};
    int f0 = tx * 5;
    #pragma unroll 4
    for (int k = 0; k < 128; ++k) {
        float xv = Xs[ty][k];
        #pragma unroll
        for (int j = 0; j < 5; ++j) acc[j] = fmaf(xv, Ws[k][f0 + j], acc[j]);
    }
    float di = dinv[node0 + ty];
    __half* yp = Y + (size_t)(node0 + ty) * 40 + f0;
    #pragma unroll
    for (int j = 0; j < 5; ++j) yp[j] = __float2half_rn(acc[j] * di);
}

// ---------------- aggregation (row-major fp16 H pre-scaled by dinv[src]) --------

__global__ __launch_bounds__(256) void agg128_kernel(const __half* __restrict__ H,
        const int* __restrict__ rowptr, const int* __restrict__ srcs,
        const float* __restrict__ dinv, const float* __restrict__ bias,
        __half* __restrict__ Bout) {
    int wave = threadIdx.x >> 6;
    int lane = threadIdx.x & 63;
    int node = blockIdx.x * 4 + wave;
    int beg = rowptr[node], end = rowptr[node + 1];
    int c = lane * 2;
    float a0 = 0.f, a1 = 0.f, b0 = 0.f, b1 = 0.f;
    int e = beg;
    for (; e + 3 < end; e += 4) {
        int s0 = srcs[e], s1 = srcs[e + 1], s2 = srcs[e + 2], s3 = srcs[e + 3];
        float2 f0 = __half22float2(*(const __half2*)(H + (size_t)s0 * 128 + c));
        float2 f1 = __half22float2(*(const __half2*)(H + (size_t)s1 * 128 + c));
        float2 f2 = __half22float2(*(const __half2*)(H + (size_t)s2 * 128 + c));
        float2 f3 = __half22float2(*(const __half2*)(H + (size_t)s3 * 128 + c));
        a0 += f0.x + f1.x; a1 += f0.y + f1.y;
        b0 += f2.x + f3.x; b1 += f2.y + f3.y;
    }
    for (; e < end; ++e) {
        int s = srcs[e];
        float2 f = __half22float2(*(const __half2*)(H + (size_t)s * 128 + c));
        a0 += f.x; a1 += f.y;
    }
    float di = dinv[node];
    float2 hs = __half22float2(*(const __half2*)(H + (size_t)node * 128 + c));
    a0 = di * (a0 + b0 + hs.x) + bias[c];
    a1 = di * (a1 + b1 + hs.y) + bias[c + 1];
    __half2 hv;
    hv.x = __float2half_rn(a0); hv.y = __float2half_rn(a1);
    *(__half2*)(Bout + (size_t)node * 128 + c) = hv;
}

__global__ __launch_bounds__(256) void agg40_softmax_kernel(const __half* __restrict__ H,
        const int* __restrict__ rowptr, const int* __restrict__ srcs,
        const float* __restrict__ dinv, const float* __restrict__ bias,
        float* __restrict__ out) {
    int wave = threadIdx.x >> 6;
    int lane = threadIdx.x & 63;
    int node = blockIdx.x * 4 + wave;
    int beg = rowptr[node], end = rowptr[node + 1];
    bool act = lane < 40;
    int ln = act ? lane : 0;
    float a0 = 0.f, a1 = 0.f, a2 = 0.f, a3 = 0.f;
    int e = beg;
    for (; e + 3 < end; e += 4) {
        int s0 = srcs[e], s1 = srcs[e + 1], s2 = srcs[e + 2], s3 = srcs[e + 3];
        a0 += __half2float(H[(size_t)s0 * 40 + ln]);
        a1 += __half2float(H[(size_t)s1 * 40 + ln]);
        a2 += __half2float(H[(size_t)s2 * 40 + ln]);
        a3 += __half2float(H[(size_t)s3 * 40 + ln]);
    }
    for (; e < end; ++e) a0 += __half2float(H[(size_t)srcs[e] * 40 + ln]);
    float di = dinv[node];
    float hs = __half2float(H[(size_t)node * 40 + ln]);
    float v = act ? (di * (a0 + a1 + a2 + a3 + hs) + bias[ln]) : -3.0e38f;
    float m = v;
    #pragma unroll
    for (int off = 32; off > 0; off >>= 1) m = fmaxf(m, __shfl_xor(m, off));
    float ev = act ? expf(v - m) : 0.f;
    float ssum = ev;
    #pragma unroll
    for (int off = 32; off > 0; off >>= 1) ssum += __shfl_xor(ssum, off);
    if (act) out[(size_t)node * 40 + lane] = ev / ssum;
}

// ---------------- launch ----------------

extern "C" void kernel_launch(void* const* d_in, const int* in_sizes, int n_in,
                              void* d_out, int out_size, void* d_ws, size_t ws_size,
                              hipStream_t stream) {
    const float* x   = (const float*)d_in[0];
    const int*   ei  = (const int*)d_in[1];
    const float* W1  = (const float*)d_in[2];
    const float* b1  = (const float*)d_in[3];
    const float* g1  = (const float*)d_in[4];
    const float* be1 = (const float*)d_in[5];
    const float* W2  = (const float*)d_in[6];
    const float* b2  = (const float*)d_in[7];
    const float* g2  = (const float*)d_in[8];
    const float* be2 = (const float*)d_in[9];
    const float* W3  = (const float*)d_in[10];
    const float* b3  = (const float*)d_in[11];
    float* out = (float*)d_out;
    const int* src = ei;
    const int* dst = ei + NE;

    char* p = (char*)d_ws;
    auto alloc = [&](size_t bytes) { char* r = p; p += (bytes + 255) & ~255ull; return r; };
    int*    rowptr    = (int*)   alloc((size_t)(NN + 1) * 4);
    int*    srcsorted = (int*)   alloc((size_t)NE * 4);
    float*  dinv      = (float*) alloc((size_t)NN * 4);
    float*  sc        = (float*) alloc(256 * 4);
    int*    G         = (int*)   alloc((size_t)GN * 4);
    int*    bsum      = (int*)   alloc((size_t)SNB * 4);
    int*    boff      = (int*)   alloc((size_t)SNB * 4);
    float*  stats2    = (float*) alloc(512 * 4);
    __half* Wth       = (__half*)alloc((size_t)2 * 16384 * 2);
    __half* A         = (__half*)alloc((size_t)NN * 128 * 2);
    __half* Bh        = (__half*)alloc((size_t)NN * 128 * 2);
    int*    ebuf      = (int*)A;   // A unused until layer-1 GEMM

    // prep
    wprep_kernel<<<256, 128, 0, stream>>>(W1, W2, Wth);
    p1hist_kernel<<<NW1, 256, 0, stream>>>(dst, G);
    gscan1_kernel<<<SNB, 256, 0, stream>>>(G, bsum);
    gscan2_kernel<<<1, 512, 0, stream>>>(bsum, boff);
    gscan3_kernel<<<SNB, 256, 0, stream>>>(G, boff);
    p1fill_kernel<<<NW1, 256, 0, stream>>>(src, dst, G, ebuf);
    p2build_kernel<<<NBUCK, 256, 0, stream>>>(ebuf, G, rowptr, srcsorted, dinv);
    hipMemsetAsync(stats2, 0, 512 * 4, stream);

    const int GB = (NN + 63) / 64;   // 1563
    // layer 1
    gemm128m_kernel<false, float><<<GB, 256, 0, stream>>>(x, Wth, nullptr, dinv, A);
    agg128_kernel<<<NN / 4, 256, 0, stream>>>(A, rowptr, srcsorted, dinv, b1, Bh);
    bnstats_kernel<<<1024, 256, 0, stream>>>(Bh, stats2);
    bnfinal_kernel<<<1, 128, 0, stream>>>(stats2, g1, be1, sc);
    // layer 2
    gemm128m_kernel<true, __half><<<GB, 256, 0, stream>>>(Bh, Wth + 16384, sc, dinv, A);
    agg128_kernel<<<NN / 4, 256, 0, stream>>>(A, rowptr, srcsorted, dinv, b2, Bh);
    bnstats_kernel<<<1024, 256, 0, stream>>>(Bh, stats2 + 256);
    bnfinal_kernel<<<1, 128, 0, stream>>>(stats2 + 256, g2, be2, sc);
    // layer 3
    gemm40_kernel<<<NN / 32, dim3(8, 32), 0, stream>>>(Bh, W3, sc, dinv, A);
    agg40_softmax_kernel<<<NN / 4, 256, 0, stream>>>(A, rowptr, srcsorted, dinv, b3, out);
}

// Round 10
// 434.915 us; speedup vs baseline: 2.4634x; 1.7880x over previous
//
#include <hip/hip_runtime.h>
#include <hip/hip_fp16.h>

#define NN   100000
#define NE   1600000
#define NBUCK 391                 // ceil(NN/256) buckets of 256 nodes
#define NW1   512                 // pass-1 workgroups
#define CH1   (NE / NW1)          // 3125 edges per wg
#define GN    (NBUCK * NW1)       // 200192 scan entries
#define SC    512
#define SNB   (GN / SC)           // 391 scan blocks
#define BNB   512                 // bnstats blocks
constexpr float EPSV = 1e-5f;

typedef _Float16 f16x8 __attribute__((ext_vector_type(8)));
typedef float    f32x4 __attribute__((ext_vector_type(4)));

// ---------------- graph prep: 2-level bucket CSR build ----------------

__global__ __launch_bounds__(256) void p1hist_kernel(const int* __restrict__ dst,
                                                     int* __restrict__ G) {
    __shared__ int h[NBUCK];
    int t = threadIdx.x, wg = blockIdx.x;
    for (int i = t; i < NBUCK; i += 256) h[i] = 0;
    __syncthreads();
    int base = wg * CH1;
    for (int e = base + t; e < base + CH1; e += 256)
        atomicAdd(&h[dst[e] >> 8], 1);
    __syncthreads();
    for (int i = t; i < NBUCK; i += 256) G[i * NW1 + wg] = h[i];
}

__global__ __launch_bounds__(256) void gscan1_kernel(const int* __restrict__ G,
                                                     int* __restrict__ bsum) {
    __shared__ int red[256];
    int t = threadIdx.x;
    int base = blockIdx.x * SC + t * 2;
    red[t] = G[base] + G[base + 1];
    __syncthreads();
    #pragma unroll
    for (int off = 128; off > 0; off >>= 1) {
        if (t < off) red[t] += red[t + off];
        __syncthreads();
    }
    if (t == 0) bsum[blockIdx.x] = red[0];
}

__global__ __launch_bounds__(512) void gscan2_kernel(const int* __restrict__ bsum,
                                                     int* __restrict__ boff) {
    __shared__ int s[512];
    int t = threadIdx.x;
    int v = (t < SNB) ? bsum[t] : 0;
    s[t] = v;
    __syncthreads();
    #pragma unroll
    for (int off = 1; off < 512; off <<= 1) {
        int u = (t >= off) ? s[t - off] : 0;
        __syncthreads();
        s[t] += u;
        __syncthreads();
    }
    if (t < SNB) boff[t] = s[t] - v;   // exclusive
}

__global__ __launch_bounds__(256) void gscan3_kernel(int* __restrict__ G,
                                                     const int* __restrict__ boff) {
    __shared__ int s[256];
    int t = threadIdx.x;
    int base = blockIdx.x * SC + t * 2;
    int c0 = G[base], c1 = G[base + 1];
    int pair = c0 + c1;
    s[t] = pair;
    __syncthreads();
    #pragma unroll
    for (int off = 1; off < 256; off <<= 1) {
        int u = (t >= off) ? s[t - off] : 0;
        __syncthreads();
        s[t] += u;
        __syncthreads();
    }
    int excl = boff[blockIdx.x] + s[t] - pair;
    G[base]     = excl;
    G[base + 1] = excl + c0;
}

__global__ __launch_bounds__(256) void p1fill_kernel(const int* __restrict__ src,
                                                     const int* __restrict__ dst,
                                                     const int* __restrict__ G,
                                                     int* __restrict__ ebuf) {
    __shared__ int cur[NBUCK];
    int t = threadIdx.x, wg = blockIdx.x;
    for (int i = t; i < NBUCK; i += 256) cur[i] = G[i * NW1 + wg];
    __syncthreads();
    int base = wg * CH1;
    for (int e = base + t; e < base + CH1; e += 256) {
        int d = dst[e];
        int pos = atomicAdd(&cur[d >> 8], 1);
        ebuf[pos] = src[e] | ((d & 255) << 17);
    }
}

__global__ __launch_bounds__(256) void p2build_kernel(const int* __restrict__ ebuf,
                                                      const int* __restrict__ G,
                                                      int* __restrict__ rowptr,
                                                      int* __restrict__ srcsorted,
                                                      float* __restrict__ dinv) {
    __shared__ int cnt[256];
    __shared__ int s[256];
    __shared__ int cur[256];
    int t = threadIdx.x, b = blockIdx.x;
    int base = G[b * NW1];
    int endp = (b == NBUCK - 1) ? NE : G[(b + 1) * NW1];
    cnt[t] = 0;
    __syncthreads();
    for (int e = base + t; e < endp; e += 256)
        atomicAdd(&cnt[ebuf[e] >> 17], 1);
    __syncthreads();
    int c = cnt[t];
    s[t] = c;
    __syncthreads();
    #pragma unroll
    for (int off = 1; off < 256; off <<= 1) {
        int u = (t >= off) ? s[t - off] : 0;
        __syncthreads();
        s[t] += u;
        __syncthreads();
    }
    int excl = s[t] - c;
    int node = b * 256 + t;
    if (node < NN) {
        rowptr[node] = base + excl;
        dinv[node]   = rsqrtf((float)c + 1.0f);
    }
    cur[t] = base + excl;
    __syncthreads();
    for (int e = base + t; e < endp; e += 256) {
        int p = ebuf[e];
        int pos = atomicAdd(&cur[p >> 17], 1);
        srcsorted[pos] = p & 0x1FFFF;
    }
    if (b == NBUCK - 1 && t == 0) rowptr[NN] = NE;
}

// ---------------- weight prep: W[k][n] fp32 -> Wt[n][k] fp16 ----------------

__global__ void wprep_kernel(const float* __restrict__ W1, const float* __restrict__ W2,
                             __half* __restrict__ Wt) {
    int b = blockIdx.x;
    int layer = b >> 7, n = b & 127, k = threadIdx.x;
    const float* W = layer ? W2 : W1;
    Wt[layer * 16384 + n * 128 + k] = __float2half_rn(W[k * 128 + n]);
}

// ---------------- batchnorm stats: atomic-free 2-stage reduction ----------------
// stage 1: 512 blocks, register accumulate + LDS cross-wave reduce, plain store
// partial[bid*256 + {0..127: sum(f), 128..255: sumsq(f)}]

__global__ __launch_bounds__(256) void bnstats_kernel(const __half* __restrict__ X,
                                                      float* __restrict__ partial) {
    __shared__ float red[4][256];
    int t = threadIdx.x;
    int f2 = t & 63, rg = t >> 6;        // lane -> half2 col, wave -> row group
    const __half2* base = (const __half2*)X + f2;
    float s0 = 0.f, s1 = 0.f, q0 = 0.f, q1 = 0.f;
    for (int r = blockIdx.x * 4 + rg; r < NN; r += BNB * 4) {
        float2 v = __half22float2(base[(size_t)r * 64]);
        s0 += v.x; s1 += v.y; q0 += v.x * v.x; q1 += v.y * v.y;
    }
    red[rg][f2 * 4 + 0] = s0;
    red[rg][f2 * 4 + 1] = s1;
    red[rg][f2 * 4 + 2] = q0;
    red[rg][f2 * 4 + 3] = q1;
    __syncthreads();
    // thread t -> (kind = t>>7, f = t&127); slot = (f>>1)*4 + (f&1) + kind*2
    int kind = t >> 7, f = t & 127;
    int slot = (f >> 1) * 4 + (f & 1) + kind * 2;
    float v = red[0][slot] + red[1][slot] + red[2][slot] + red[3][slot];
    partial[blockIdx.x * 256 + kind * 128 + f] = v;
}

// stage 2: one block reduces 512 partial slices -> sc[256]
__global__ __launch_bounds__(256) void bnfinal_kernel(const float* __restrict__ partial,
                                                      const float* __restrict__ g,
                                                      const float* __restrict__ be,
                                                      float* __restrict__ sc) {
    __shared__ float red[256];
    int t = threadIdx.x;
    float v = 0.f;
    #pragma unroll 8
    for (int sl = 0; sl < BNB; ++sl) v += partial[sl * 256 + t];
    red[t] = v;
    __syncthreads();
    if (t < 128) {
        float s = red[t], q = red[128 + t];
        float mu  = s * (1.0f / NN);
        float var = q * (1.0f / NN) - mu * mu;
        float rstd = rsqrtf(var + EPSV);
        float scale = g[t] * rstd;
        sc[t]       = scale;
        sc[128 + t] = be[t] - mu * scale;
    }
}

// ---------------- MFMA fp16 GEMM: 64 nodes x 128 feats, K=128 ----------------
// LDS XOR-swizzle both sides: byte = row*256 + (colByte ^ ((row&7)<<4))

__device__ __forceinline__ int swzb(int row, int colByte) {
    return row * 256 + (colByte ^ ((row & 7) << 4));
}

template<bool BN, typename TIN>
__global__ __launch_bounds__(256) void gemm128m_kernel(const TIN* __restrict__ X,
        const __half* __restrict__ Wt, const float* __restrict__ sc,
        const float* __restrict__ dinv, __half* __restrict__ Y) {
    __shared__ __align__(16) char Xs[64 * 256];
    __shared__ __align__(16) char Wts[128 * 256];
    __shared__ float dvs[64];
    int tid = threadIdx.x;
    int node0 = blockIdx.x * 64;

    {   // stage Wt (pre-transposed fp16)
        int n = tid >> 1, c0 = (tid & 1) * 64;
        const _Float16* g = (const _Float16*)Wt + n * 128 + c0;
        #pragma unroll
        for (int j = 0; j < 8; ++j) {
            f16x8 v = *(const f16x8*)(g + j * 8);
            *(f16x8*)(Wts + swzb(n, (c0 + j * 8) * 2)) = v;
        }
    }
    {   // stage X (+BN+ReLU), cvt fp16
        int r = tid >> 2, c0 = (tid & 3) * 32;
        int grow = node0 + r;
        #pragma unroll
        for (int j = 0; j < 4; ++j) {
            int c = c0 + j * 8;
            f16x8 o;
            if (grow < NN) {
                float f[8];
                if constexpr (sizeof(TIN) == 4) {
                    float4 u0 = *(const float4*)((const float*)X + (size_t)grow * 128 + c);
                    float4 u1 = *(const float4*)((const float*)X + (size_t)grow * 128 + c + 4);
                    f[0] = u0.x; f[1] = u0.y; f[2] = u0.z; f[3] = u0.w;
                    f[4] = u1.x; f[5] = u1.y; f[6] = u1.z; f[7] = u1.w;
                } else {
                    f16x8 h = *(const f16x8*)((const _Float16*)X + (size_t)grow * 128 + c);
                    #pragma unroll
                    for (int i = 0; i < 8; ++i) f[i] = (float)h[i];
                }
                #pragma unroll
                for (int i = 0; i < 8; ++i) {
                    if constexpr (BN) f[i] = fmaxf(fmaf(f[i], sc[c + i], sc[128 + c + i]), 0.f);
                    o[i] = (_Float16)f[i];
                }
            } else {
                #pragma unroll
                for (int i = 0; i < 8; ++i) o[i] = (_Float16)0.f;
            }
            *(f16x8*)(Xs + swzb(r, c * 2)) = o;
        }
    }
    if (tid < 64) dvs[tid] = (node0 + tid < NN) ? dinv[node0 + tid] : 0.f;
    __syncthreads();

    int lane = tid & 63;
    int wv   = tid >> 6;
    int n0w  = wv * 32;
    int lm   = lane & 15;
    int lg   = lane >> 4;

    f32x4 acc[4][2] = {};
    #pragma unroll
    for (int s = 0; s < 4; ++s) {
        int kb = (s * 32 + lg * 8) * 2;
        f16x8 a[4], b[2];
        #pragma unroll
        for (int i = 0; i < 4; ++i)
            a[i] = *(const f16x8*)(Xs + swzb(i * 16 + lm, kb));
        #pragma unroll
        for (int r = 0; r < 2; ++r)
            b[r] = *(const f16x8*)(Wts + swzb(n0w + r * 16 + lm, kb));
        #pragma unroll
        for (int i = 0; i < 4; ++i)
            #pragma unroll
            for (int r = 0; r < 2; ++r)
                acc[i][r] = __builtin_amdgcn_mfma_f32_16x16x32_f16(a[i], b[r], acc[i][r], 0, 0, 0);
    }

    _Float16* Yh = (_Float16*)Y;
    #pragma unroll
    for (int i = 0; i < 4; ++i) {
        #pragma unroll
        for (int q = 0; q < 4; ++q) {
            int row = i * 16 + lg * 4 + q;
            int grow = node0 + row;
            if (grow < NN) {
                float di = dvs[row];
                Yh[(size_t)grow * 128 + n0w + lm]      = (_Float16)(acc[i][0][q] * di);
                Yh[(size_t)grow * 128 + n0w + 16 + lm] = (_Float16)(acc[i][1][q] * di);
            }
        }
    }
}

// ---------------- final dense GEMM 128->40 (fp32 VALU, fp16 in) ----------------

__global__ __launch_bounds__(256) void gemm40_kernel(const __half* __restrict__ X,
        const float* __restrict__ W, const float* __restrict__ sc,
        const float* __restrict__ dinv, __half* __restrict__ Y) {
    __shared__ float Ws[128][40];
    __shared__ float Xs[32][132];
    int tx = threadIdx.x, ty = threadIdx.y;
    int tid = ty * 8 + tx;
    int node0 = blockIdx.x * 32;

    float* wf = &Ws[0][0];
    for (int idx = tid; idx < 128 * 40; idx += 256) wf[idx] = W[idx];
    for (int idx = tid * 8; idx < 32 * 128; idx += 256 * 8) {
        int n = idx >> 7, f = idx & 127;
        f16x8 h = *(const f16x8*)((const _Float16*)X + (size_t)(node0 + n) * 128 + f);
        float v[8];
        #pragma unroll
        for (int i = 0; i < 8; ++i)
            v[i] = fmaxf(fmaf((float)h[i], sc[f + i], sc[128 + f + i]), 0.f);
        *(float4*)&Xs[n][f]     = make_float4(v[0], v[1], v[2], v[3]);
        *(float4*)&Xs[n][f + 4] = make_float4(v[4], v[5], v[6], v[7]);
    }
    __syncthreads();

    float acc[5] = {0, 0, 0, 0, 0};
    int f0 = tx * 5;
    #pragma unroll 4
    for (int k = 0; k < 128; ++k) {
        float xv = Xs[ty][k];
        #pragma unroll
        for (int j = 0; j < 5; ++j) acc[j] = fmaf(xv, Ws[k][f0 + j], acc[j]);
    }
    float di = dinv[node0 + ty];
    __half* yp = Y + (size_t)(node0 + ty) * 40 + f0;
    #pragma unroll
    for (int j = 0; j < 5; ++j) yp[j] = __float2half_rn(acc[j] * di);
}

// ---------------- aggregation (row-major fp16 H pre-scaled by dinv[src]) --------

__global__ __launch_bounds__(256) void agg128_kernel(const __half* __restrict__ H,
        const int* __restrict__ rowptr, const int* __restrict__ srcs,
        const float* __restrict__ dinv, const float* __restrict__ bias,
        __half* __restrict__ Bout) {
    int wave = threadIdx.x >> 6;
    int lane = threadIdx.x & 63;
    int node = blockIdx.x * 4 + wave;
    int beg = rowptr[node], end = rowptr[node + 1];
    int c = lane * 2;
    float a0 = 0.f, a1 = 0.f, b0 = 0.f, b1 = 0.f;
    int e = beg;
    for (; e + 3 < end; e += 4) {
        int s0 = srcs[e], s1 = srcs[e + 1], s2 = srcs[e + 2], s3 = srcs[e + 3];
        float2 f0 = __half22float2(*(const __half2*)(H + (size_t)s0 * 128 + c));
        float2 f1 = __half22float2(*(const __half2*)(H + (size_t)s1 * 128 + c));
        float2 f2 = __half22float2(*(const __half2*)(H + (size_t)s2 * 128 + c));
        float2 f3 = __half22float2(*(const __half2*)(H + (size_t)s3 * 128 + c));
        a0 += f0.x + f1.x; a1 += f0.y + f1.y;
        b0 += f2.x + f3.x; b1 += f2.y + f3.y;
    }
    for (; e < end; ++e) {
        int s = srcs[e];
        float2 f = __half22float2(*(const __half2*)(H + (size_t)s * 128 + c));
        a0 += f.x; a1 += f.y;
    }
    float di = dinv[node];
    float2 hs = __half22float2(*(const __half2*)(H + (size_t)node * 128 + c));
    a0 = di * (a0 + b0 + hs.x) + bias[c];
    a1 = di * (a1 + b1 + hs.y) + bias[c + 1];
    __half2 hv;
    hv.x = __float2half_rn(a0); hv.y = __float2half_rn(a1);
    *(__half2*)(Bout + (size_t)node * 128 + c) = hv;
}

__global__ __launch_bounds__(256) void agg40_softmax_kernel(const __half* __restrict__ H,
        const int* __restrict__ rowptr, const int* __restrict__ srcs,
        const float* __restrict__ dinv, const float* __restrict__ bias,
        float* __restrict__ out) {
    int wave = threadIdx.x >> 6;
    int lane = threadIdx.x & 63;
    int node = blockIdx.x * 4 + wave;
    int beg = rowptr[node], end = rowptr[node + 1];
    bool act = lane < 40;
    int ln = act ? lane : 0;
    float a0 = 0.f, a1 = 0.f, a2 = 0.f, a3 = 0.f;
    int e = beg;
    for (; e + 3 < end; e += 4) {
        int s0 = srcs[e], s1 = srcs[e + 1], s2 = srcs[e + 2], s3 = srcs[e + 3];
        a0 += __half2float(H[(size_t)s0 * 40 + ln]);
        a1 += __half2float(H[(size_t)s1 * 40 + ln]);
        a2 += __half2float(H[(size_t)s2 * 40 + ln]);
        a3 += __half2float(H[(size_t)s3 * 40 + ln]);
    }
    for (; e < end; ++e) a0 += __half2float(H[(size_t)srcs[e] * 40 + ln]);
    float di = dinv[node];
    float hs = __half2float(H[(size_t)node * 40 + ln]);
    float v = act ? (di * (a0 + a1 + a2 + a3 + hs) + bias[ln]) : -3.0e38f;
    float m = v;
    #pragma unroll
    for (int off = 32; off > 0; off >>= 1) m = fmaxf(m, __shfl_xor(m, off));
    float ev = act ? expf(v - m) : 0.f;
    float ssum = ev;
    #pragma unroll
    for (int off = 32; off > 0; off >>= 1) ssum += __shfl_xor(ssum, off);
    if (act) out[(size_t)node * 40 + lane] = ev / ssum;
}

// ---------------- launch ----------------

extern "C" void kernel_launch(void* const* d_in, const int* in_sizes, int n_in,
                              void* d_out, int out_size, void* d_ws, size_t ws_size,
                              hipStream_t stream) {
    const float* x   = (const float*)d_in[0];
    const int*   ei  = (const int*)d_in[1];
    const float* W1  = (const float*)d_in[2];
    const float* b1  = (const float*)d_in[3];
    const float* g1  = (const float*)d_in[4];
    const float* be1 = (const float*)d_in[5];
    const float* W2  = (const float*)d_in[6];
    const float* b2  = (const float*)d_in[7];
    const float* g2  = (const float*)d_in[8];
    const float* be2 = (const float*)d_in[9];
    const float* W3  = (const float*)d_in[10];
    const float* b3  = (const float*)d_in[11];
    float* out = (float*)d_out;
    const int* src = ei;
    const int* dst = ei + NE;

    char* p = (char*)d_ws;
    auto alloc = [&](size_t bytes) { char* r = p; p += (bytes + 255) & ~255ull; return r; };
    int*    rowptr    = (int*)   alloc((size_t)(NN + 1) * 4);
    int*    srcsorted = (int*)   alloc((size_t)NE * 4);
    float*  dinv      = (float*) alloc((size_t)NN * 4);
    float*  sc        = (float*) alloc(256 * 4);
    int*    G         = (int*)   alloc((size_t)GN * 4);
    int*    bsum      = (int*)   alloc((size_t)SNB * 4);
    int*    boff      = (int*)   alloc((size_t)SNB * 4);
    float*  partial   = (float*) alloc((size_t)BNB * 256 * 4);   // 512 KB, atomic-free
    __half* Wth       = (__half*)alloc((size_t)2 * 16384 * 2);
    __half* A         = (__half*)alloc((size_t)NN * 128 * 2);
    __half* Bh        = (__half*)alloc((size_t)NN * 128 * 2);
    int*    ebuf      = (int*)A;   // A unused until layer-1 GEMM

    // prep
    wprep_kernel<<<256, 128, 0, stream>>>(W1, W2, Wth);
    p1hist_kernel<<<NW1, 256, 0, stream>>>(dst, G);
    gscan1_kernel<<<SNB, 256, 0, stream>>>(G, bsum);
    gscan2_kernel<<<1, 512, 0, stream>>>(bsum, boff);
    gscan3_kernel<<<SNB, 256, 0, stream>>>(G, boff);
    p1fill_kernel<<<NW1, 256, 0, stream>>>(src, dst, G, ebuf);
    p2build_kernel<<<NBUCK, 256, 0, stream>>>(ebuf, G, rowptr, srcsorted, dinv);

    const int GB = (NN + 63) / 64;   // 1563
    // layer 1
    gemm128m_kernel<false, float><<<GB, 256, 0, stream>>>(x, Wth, nullptr, dinv, A);
    agg128_kernel<<<NN / 4, 256, 0, stream>>>(A, rowptr, srcsorted, dinv, b1, Bh);
    bnstats_kernel<<<BNB, 256, 0, stream>>>(Bh, partial);
    bnfinal_kernel<<<1, 256, 0, stream>>>(partial, g1, be1, sc);
    // layer 2
    gemm128m_kernel<true, __half><<<GB, 256, 0, stream>>>(Bh, Wth + 16384, sc, dinv, A);
    agg128_kernel<<<NN / 4, 256, 0, stream>>>(A, rowptr, srcsorted, dinv, b2, Bh);
    bnstats_kernel<<<BNB, 256, 0, stream>>>(Bh, partial);
    bnfinal_kernel<<<1, 256, 0, stream>>>(partial, g2, be2, sc);
    // layer 3
    gemm40_kernel<<<NN / 32, dim3(8, 32), 0, stream>>>(Bh, W3, sc, dinv, A);
    agg40_softmax_kernel<<<NN / 4, 256, 0, stream>>>(A, rowptr, srcsorted, dinv, b3, out);
}

// Round 11
// 407.359 us; speedup vs baseline: 2.6300x; 1.0676x over previous
//
#include <hip/hip_runtime.h>
#include <hip/hip_fp16.h>

#define NN   100000
#define NE   1600000
#define NBUCK 391                 // ceil(NN/256) buckets of 256 nodes
#define NW1   512                 // pass-1 workgroups
#define CH1   (NE / NW1)          // 3125 edges per wg
#define GN    (NBUCK * NW1)       // 200192 scan entries
#define SC    512
#define SNB   (GN / SC)           // 391 scan blocks
#define BNB   512                 // bnstats blocks
constexpr float EPSV = 1e-5f;

typedef _Float16 f16x8 __attribute__((ext_vector_type(8)));
typedef float    f32x4 __attribute__((ext_vector_type(4)));

// ---------------- graph prep: 2-level bucket CSR build ----------------

__global__ __launch_bounds__(256) void p1hist_kernel(const int* __restrict__ dst,
                                                     int* __restrict__ G) {
    __shared__ int h[NBUCK];
    int t = threadIdx.x, wg = blockIdx.x;
    for (int i = t; i < NBUCK; i += 256) h[i] = 0;
    __syncthreads();
    int base = wg * CH1;
    for (int e = base + t; e < base + CH1; e += 256)
        atomicAdd(&h[dst[e] >> 8], 1);
    __syncthreads();
    for (int i = t; i < NBUCK; i += 256) G[i * NW1 + wg] = h[i];
}

__global__ __launch_bounds__(256) void gscan1_kernel(const int* __restrict__ G,
                                                     int* __restrict__ bsum) {
    __shared__ int red[256];
    int t = threadIdx.x;
    int base = blockIdx.x * SC + t * 2;
    red[t] = G[base] + G[base + 1];
    __syncthreads();
    #pragma unroll
    for (int off = 128; off > 0; off >>= 1) {
        if (t < off) red[t] += red[t + off];
        __syncthreads();
    }
    if (t == 0) bsum[blockIdx.x] = red[0];
}

__global__ __launch_bounds__(512) void gscan2_kernel(const int* __restrict__ bsum,
                                                     int* __restrict__ boff) {
    __shared__ int s[512];
    int t = threadIdx.x;
    int v = (t < SNB) ? bsum[t] : 0;
    s[t] = v;
    __syncthreads();
    #pragma unroll
    for (int off = 1; off < 512; off <<= 1) {
        int u = (t >= off) ? s[t - off] : 0;
        __syncthreads();
        s[t] += u;
        __syncthreads();
    }
    if (t < SNB) boff[t] = s[t] - v;   // exclusive
}

__global__ __launch_bounds__(256) void gscan3_kernel(int* __restrict__ G,
                                                     const int* __restrict__ boff) {
    __shared__ int s[256];
    int t = threadIdx.x;
    int base = blockIdx.x * SC + t * 2;
    int c0 = G[base], c1 = G[base + 1];
    int pair = c0 + c1;
    s[t] = pair;
    __syncthreads();
    #pragma unroll
    for (int off = 1; off < 256; off <<= 1) {
        int u = (t >= off) ? s[t - off] : 0;
        __syncthreads();
        s[t] += u;
        __syncthreads();
    }
    int excl = boff[blockIdx.x] + s[t] - pair;
    G[base]     = excl;
    G[base + 1] = excl + c0;
}

__global__ __launch_bounds__(256) void p1fill_kernel(const int* __restrict__ src,
                                                     const int* __restrict__ dst,
                                                     const int* __restrict__ G,
                                                     int* __restrict__ ebuf) {
    __shared__ int cur[NBUCK];
    int t = threadIdx.x, wg = blockIdx.x;
    for (int i = t; i < NBUCK; i += 256) cur[i] = G[i * NW1 + wg];
    __syncthreads();
    int base = wg * CH1;
    for (int e = base + t; e < base + CH1; e += 256) {
        int d = dst[e];
        int pos = atomicAdd(&cur[d >> 8], 1);
        ebuf[pos] = src[e] | ((d & 255) << 17);
    }
}

__global__ __launch_bounds__(256) void p2build_kernel(const int* __restrict__ ebuf,
                                                      const int* __restrict__ G,
                                                      int* __restrict__ rowptr,
                                                      int* __restrict__ srcsorted,
                                                      float* __restrict__ dinv) {
    __shared__ int cnt[256];
    __shared__ int s[256];
    __shared__ int cur[256];
    int t = threadIdx.x, b = blockIdx.x;
    int base = G[b * NW1];
    int endp = (b == NBUCK - 1) ? NE : G[(b + 1) * NW1];
    cnt[t] = 0;
    __syncthreads();
    for (int e = base + t; e < endp; e += 256)
        atomicAdd(&cnt[ebuf[e] >> 17], 1);
    __syncthreads();
    int c = cnt[t];
    s[t] = c;
    __syncthreads();
    #pragma unroll
    for (int off = 1; off < 256; off <<= 1) {
        int u = (t >= off) ? s[t - off] : 0;
        __syncthreads();
        s[t] += u;
        __syncthreads();
    }
    int excl = s[t] - c;
    int node = b * 256 + t;
    if (node < NN) {
        rowptr[node] = base + excl;
        dinv[node]   = rsqrtf((float)c + 1.0f);
    }
    cur[t] = base + excl;
    __syncthreads();
    for (int e = base + t; e < endp; e += 256) {
        int p = ebuf[e];
        int pos = atomicAdd(&cur[p >> 17], 1);
        srcsorted[pos] = p & 0x1FFFF;
    }
    if (b == NBUCK - 1 && t == 0) rowptr[NN] = NE;
}

// ---------------- weight prep: W[k][n] fp32 -> Wt[n][k] fp16 ----------------

__global__ void wprep_kernel(const float* __restrict__ W1, const float* __restrict__ W2,
                             __half* __restrict__ Wt) {
    int b = blockIdx.x;
    int layer = b >> 7, n = b & 127, k = threadIdx.x;
    const float* W = layer ? W2 : W1;
    Wt[layer * 16384 + n * 128 + k] = __float2half_rn(W[k * 128 + n]);
}

// ---------------- batchnorm stats: atomic-free 2-stage reduction ----------------

__global__ __launch_bounds__(256) void bnstats_kernel(const __half* __restrict__ X,
                                                      float* __restrict__ partial) {
    __shared__ float red[4][256];
    int t = threadIdx.x;
    int f2 = t & 63, rg = t >> 6;
    const __half2* base = (const __half2*)X + f2;
    float s0 = 0.f, s1 = 0.f, q0 = 0.f, q1 = 0.f;
    for (int r = blockIdx.x * 4 + rg; r < NN; r += BNB * 4) {
        float2 v = __half22float2(base[(size_t)r * 64]);
        s0 += v.x; s1 += v.y; q0 += v.x * v.x; q1 += v.y * v.y;
    }
    red[rg][f2 * 4 + 0] = s0;
    red[rg][f2 * 4 + 1] = s1;
    red[rg][f2 * 4 + 2] = q0;
    red[rg][f2 * 4 + 3] = q1;
    __syncthreads();
    int kind = t >> 7, f = t & 127;
    int slot = (f >> 1) * 4 + (f & 1) + kind * 2;
    float v = red[0][slot] + red[1][slot] + red[2][slot] + red[3][slot];
    partial[blockIdx.x * 256 + kind * 128 + f] = v;
}

__global__ __launch_bounds__(256) void bnfinal_kernel(const float* __restrict__ partial,
                                                      const float* __restrict__ g,
                                                      const float* __restrict__ be,
                                                      float* __restrict__ sc) {
    __shared__ float red[256];
    int t = threadIdx.x;
    float v = 0.f;
    #pragma unroll 8
    for (int sl = 0; sl < BNB; ++sl) v += partial[sl * 256 + t];
    red[t] = v;
    __syncthreads();
    if (t < 128) {
        float s = red[t], q = red[128 + t];
        float mu  = s * (1.0f / NN);
        float var = q * (1.0f / NN) - mu * mu;
        float rstd = rsqrtf(var + EPSV);
        float scale = g[t] * rstd;
        sc[t]       = scale;
        sc[128 + t] = be[t] - mu * scale;
    }
}

// ---------------- MFMA fp16 GEMM: 64 nodes x 128 feats, K=128 ----------------

__device__ __forceinline__ int swzb(int row, int colByte) {
    return row * 256 + (colByte ^ ((row & 7) << 4));
}

template<bool BN, typename TIN>
__global__ __launch_bounds__(256) void gemm128m_kernel(const TIN* __restrict__ X,
        const __half* __restrict__ Wt, const float* __restrict__ sc,
        const float* __restrict__ dinv, __half* __restrict__ Y) {
    __shared__ __align__(16) char Xs[64 * 256];
    __shared__ __align__(16) char Wts[128 * 256];
    __shared__ float dvs[64];
    int tid = threadIdx.x;
    int node0 = blockIdx.x * 64;

    {   // stage Wt (pre-transposed fp16)
        int n = tid >> 1, c0 = (tid & 1) * 64;
        const _Float16* g = (const _Float16*)Wt + n * 128 + c0;
        #pragma unroll
        for (int j = 0; j < 8; ++j) {
            f16x8 v = *(const f16x8*)(g + j * 8);
            *(f16x8*)(Wts + swzb(n, (c0 + j * 8) * 2)) = v;
        }
    }
    {   // stage X (+BN+ReLU), cvt fp16
        int r = tid >> 2, c0 = (tid & 3) * 32;
        int grow = node0 + r;
        #pragma unroll
        for (int j = 0; j < 4; ++j) {
            int c = c0 + j * 8;
            f16x8 o;
            if (grow < NN) {
                float f[8];
                if constexpr (sizeof(TIN) == 4) {
                    float4 u0 = *(const float4*)((const float*)X + (size_t)grow * 128 + c);
                    float4 u1 = *(const float4*)((const float*)X + (size_t)grow * 128 + c + 4);
                    f[0] = u0.x; f[1] = u0.y; f[2] = u0.z; f[3] = u0.w;
                    f[4] = u1.x; f[5] = u1.y; f[6] = u1.z; f[7] = u1.w;
                } else {
                    f16x8 h = *(const f16x8*)((const _Float16*)X + (size_t)grow * 128 + c);
                    #pragma unroll
                    for (int i = 0; i < 8; ++i) f[i] = (float)h[i];
                }
                #pragma unroll
                for (int i = 0; i < 8; ++i) {
                    if constexpr (BN) f[i] = fmaxf(fmaf(f[i], sc[c + i], sc[128 + c + i]), 0.f);
                    o[i] = (_Float16)f[i];
                }
            } else {
                #pragma unroll
                for (int i = 0; i < 8; ++i) o[i] = (_Float16)0.f;
            }
            *(f16x8*)(Xs + swzb(r, c * 2)) = o;
        }
    }
    if (tid < 64) dvs[tid] = (node0 + tid < NN) ? dinv[node0 + tid] : 0.f;
    __syncthreads();

    int lane = tid & 63;
    int wv   = tid >> 6;
    int n0w  = wv * 32;
    int lm   = lane & 15;
    int lg   = lane >> 4;

    f32x4 acc[4][2] = {};
    #pragma unroll
    for (int s = 0; s < 4; ++s) {
        int kb = (s * 32 + lg * 8) * 2;
        f16x8 a[4], b[2];
        #pragma unroll
        for (int i = 0; i < 4; ++i)
            a[i] = *(const f16x8*)(Xs + swzb(i * 16 + lm, kb));
        #pragma unroll
        for (int r = 0; r < 2; ++r)
            b[r] = *(const f16x8*)(Wts + swzb(n0w + r * 16 + lm, kb));
        #pragma unroll
        for (int i = 0; i < 4; ++i)
            #pragma unroll
            for (int r = 0; r < 2; ++r)
                acc[i][r] = __builtin_amdgcn_mfma_f32_16x16x32_f16(a[i], b[r], acc[i][r], 0, 0, 0);
    }

    _Float16* Yh = (_Float16*)Y;
    #pragma unroll
    for (int i = 0; i < 4; ++i) {
        #pragma unroll
        for (int q = 0; q < 4; ++q) {
            int row = i * 16 + lg * 4 + q;
            int grow = node0 + row;
            if (grow < NN) {
                float di = dvs[row];
                Yh[(size_t)grow * 128 + n0w + lm]      = (_Float16)(acc[i][0][q] * di);
                Yh[(size_t)grow * 128 + n0w + 16 + lm] = (_Float16)(acc[i][1][q] * di);
            }
        }
    }
}

// ---------------- final dense GEMM 128->40 (fp32 VALU, fp16 in, pad out 64) ------

__global__ __launch_bounds__(256) void gemm40_kernel(const __half* __restrict__ X,
        const float* __restrict__ W, const float* __restrict__ sc,
        const float* __restrict__ dinv, __half* __restrict__ Y) {
    __shared__ float Ws[128][40];
    __shared__ float Xs[32][132];
    int tx = threadIdx.x, ty = threadIdx.y;
    int tid = ty * 8 + tx;
    int node0 = blockIdx.x * 32;

    float* wf = &Ws[0][0];
    for (int idx = tid; idx < 128 * 40; idx += 256) wf[idx] = W[idx];
    for (int idx = tid * 8; idx < 32 * 128; idx += 256 * 8) {
        int n = idx >> 7, f = idx & 127;
        f16x8 h = *(const f16x8*)((const _Float16*)X + (size_t)(node0 + n) * 128 + f);
        float v[8];
        #pragma unroll
        for (int i = 0; i < 8; ++i)
            v[i] = fmaxf(fmaf((float)h[i], sc[f + i], sc[128 + f + i]), 0.f);
        *(float4*)&Xs[n][f]     = make_float4(v[0], v[1], v[2], v[3]);
        *(float4*)&Xs[n][f + 4] = make_float4(v[4], v[5], v[6], v[7]);
    }
    __syncthreads();

    float acc[5] = {0, 0, 0, 0, 0};
    int f0 = tx * 5;
    #pragma unroll 4
    for (int k = 0; k < 128; ++k) {
        float xv = Xs[ty][k];
        #pragma unroll
        for (int j = 0; j < 5; ++j) acc[j] = fmaf(xv, Ws[k][f0 + j], acc[j]);
    }
    float di = dinv[node0 + ty];
    __half* yp = Y + (size_t)(node0 + ty) * 64 + f0;   // padded stride 64
    #pragma unroll
    for (int j = 0; j < 5; ++j) yp[j] = __float2half_rn(acc[j] * di);
}

// ---------------- aggregation (row-major fp16 H pre-scaled, 8-deep ILP) ---------

__global__ __launch_bounds__(256) void agg128_kernel(const __half* __restrict__ H,
        const int* __restrict__ rowptr, const int* __restrict__ srcs,
        const float* __restrict__ dinv, const float* __restrict__ bias,
        __half* __restrict__ Bout) {
    int wave = threadIdx.x >> 6;
    int lane = threadIdx.x & 63;
    int node = blockIdx.x * 4 + wave;
    int beg = rowptr[node], end = rowptr[node + 1];
    const __half2* Hc = (const __half2*)H + lane;    // row r at Hc[r*64]
    float a0 = 0.f, a1 = 0.f, b0 = 0.f, b1 = 0.f;
    float c0 = 0.f, c1 = 0.f, d0 = 0.f, d1 = 0.f;
    int e = beg;
    for (; e + 7 < end; e += 8) {
        int s0 = srcs[e],     s1 = srcs[e + 1], s2 = srcs[e + 2], s3 = srcs[e + 3];
        int s4 = srcs[e + 4], s5 = srcs[e + 5], s6 = srcs[e + 6], s7 = srcs[e + 7];
        float2 f0 = __half22float2(Hc[(size_t)s0 * 64]);
        float2 f1 = __half22float2(Hc[(size_t)s1 * 64]);
        float2 f2 = __half22float2(Hc[(size_t)s2 * 64]);
        float2 f3 = __half22float2(Hc[(size_t)s3 * 64]);
        float2 f4 = __half22float2(Hc[(size_t)s4 * 64]);
        float2 f5 = __half22float2(Hc[(size_t)s5 * 64]);
        float2 f6 = __half22float2(Hc[(size_t)s6 * 64]);
        float2 f7 = __half22float2(Hc[(size_t)s7 * 64]);
        a0 += f0.x + f1.x; a1 += f0.y + f1.y;
        b0 += f2.x + f3.x; b1 += f2.y + f3.y;
        c0 += f4.x + f5.x; c1 += f4.y + f5.y;
        d0 += f6.x + f7.x; d1 += f6.y + f7.y;
    }
    if (e + 3 < end) {
        int s0 = srcs[e], s1 = srcs[e + 1], s2 = srcs[e + 2], s3 = srcs[e + 3];
        float2 f0 = __half22float2(Hc[(size_t)s0 * 64]);
        float2 f1 = __half22float2(Hc[(size_t)s1 * 64]);
        float2 f2 = __half22float2(Hc[(size_t)s2 * 64]);
        float2 f3 = __half22float2(Hc[(size_t)s3 * 64]);
        a0 += f0.x + f1.x; a1 += f0.y + f1.y;
        b0 += f2.x + f3.x; b1 += f2.y + f3.y;
        e += 4;
    }
    for (; e < end; ++e) {
        float2 f = __half22float2(Hc[(size_t)srcs[e] * 64]);
        a0 += f.x; a1 += f.y;
    }
    float di = dinv[node];
    float2 hs = __half22float2(Hc[(size_t)node * 64]);
    a0 = di * (a0 + b0 + c0 + d0 + hs.x) + bias[lane * 2];
    a1 = di * (a1 + b1 + c1 + d1 + hs.y) + bias[lane * 2 + 1];
    __half2 hv;
    hv.x = __float2half_rn(a0); hv.y = __float2half_rn(a1);
    *((__half2*)Bout + (size_t)node * 64 + lane) = hv;
}

// final: 64-elem padded H3 rows, 8-deep ILP, fused softmax
__global__ __launch_bounds__(256) void agg40_softmax_kernel(const __half* __restrict__ H,
        const int* __restrict__ rowptr, const int* __restrict__ srcs,
        const float* __restrict__ dinv, const float* __restrict__ bias,
        float* __restrict__ out) {
    int wave = threadIdx.x >> 6;
    int lane = threadIdx.x & 63;
    int node = blockIdx.x * 4 + wave;
    int beg = rowptr[node], end = rowptr[node + 1];
    bool act = lane < 40;
    const _Float16* Hc = (const _Float16*)H + lane;   // padded stride 64
    float a0 = 0.f, a1 = 0.f, a2 = 0.f, a3 = 0.f;
    float a4 = 0.f, a5 = 0.f, a6 = 0.f, a7 = 0.f;
    int e = beg;
    for (; e + 7 < end; e += 8) {
        a0 += (float)Hc[(size_t)srcs[e]     * 64];
        a1 += (float)Hc[(size_t)srcs[e + 1] * 64];
        a2 += (float)Hc[(size_t)srcs[e + 2] * 64];
        a3 += (float)Hc[(size_t)srcs[e + 3] * 64];
        a4 += (float)Hc[(size_t)srcs[e + 4] * 64];
        a5 += (float)Hc[(size_t)srcs[e + 5] * 64];
        a6 += (float)Hc[(size_t)srcs[e + 6] * 64];
        a7 += (float)Hc[(size_t)srcs[e + 7] * 64];
    }
    if (e + 3 < end) {
        a0 += (float)Hc[(size_t)srcs[e]     * 64];
        a1 += (float)Hc[(size_t)srcs[e + 1] * 64];
        a2 += (float)Hc[(size_t)srcs[e + 2] * 64];
        a3 += (float)Hc[(size_t)srcs[e + 3] * 64];
        e += 4;
    }
    for (; e < end; ++e) a0 += (float)Hc[(size_t)srcs[e] * 64];
    float di = dinv[node];
    float hs = (float)Hc[(size_t)node * 64];
    float v = act ? (di * (a0 + a1 + a2 + a3 + a4 + a5 + a6 + a7 + hs) + bias[lane]) : -3.0e38f;
    float m = v;
    #pragma unroll
    for (int off = 32; off > 0; off >>= 1) m = fmaxf(m, __shfl_xor(m, off));
    float ev = act ? expf(v - m) : 0.f;
    float ssum = ev;
    #pragma unroll
    for (int off = 32; off > 0; off >>= 1) ssum += __shfl_xor(ssum, off);
    if (act) out[(size_t)node * 40 + lane] = ev / ssum;
}

// ---------------- launch ----------------

extern "C" void kernel_launch(void* const* d_in, const int* in_sizes, int n_in,
                              void* d_out, int out_size, void* d_ws, size_t ws_size,
                              hipStream_t stream) {
    const float* x   = (const float*)d_in[0];
    const int*   ei  = (const int*)d_in[1];
    const float* W1  = (const float*)d_in[2];
    const float* b1  = (const float*)d_in[3];
    const float* g1  = (const float*)d_in[4];
    const float* be1 = (const float*)d_in[5];
    const float* W2  = (const float*)d_in[6];
    const float* b2  = (const float*)d_in[7];
    const float* g2  = (const float*)d_in[8];
    const float* be2 = (const float*)d_in[9];
    const float* W3  = (const float*)d_in[10];
    const float* b3  = (const float*)d_in[11];
    float* out = (float*)d_out;
    const int* src = ei;
    const int* dst = ei + NE;

    char* p = (char*)d_ws;
    auto alloc = [&](size_t bytes) { char* r = p; p += (bytes + 255) & ~255ull; return r; };
    int*    rowptr    = (int*)   alloc((size_t)(NN + 1) * 4);
    int*    srcsorted = (int*)   alloc((size_t)NE * 4);
    float*  dinv      = (float*) alloc((size_t)NN * 4);
    float*  sc        = (float*) alloc(256 * 4);
    int*    G         = (int*)   alloc((size_t)GN * 4);
    int*    bsum      = (int*)   alloc((size_t)SNB * 4);
    int*    boff      = (int*)   alloc((size_t)SNB * 4);
    float*  partial   = (float*) alloc((size_t)BNB * 256 * 4);
    __half* Wth       = (__half*)alloc((size_t)2 * 16384 * 2);
    __half* A         = (__half*)alloc((size_t)NN * 128 * 2);
    __half* Bh        = (__half*)alloc((size_t)NN * 128 * 2);
    int*    ebuf      = (int*)A;   // A unused until layer-1 GEMM

    // prep
    wprep_kernel<<<256, 128, 0, stream>>>(W1, W2, Wth);
    p1hist_kernel<<<NW1, 256, 0, stream>>>(dst, G);
    gscan1_kernel<<<SNB, 256, 0, stream>>>(G, bsum);
    gscan2_kernel<<<1, 512, 0, stream>>>(bsum, boff);
    gscan3_kernel<<<SNB, 256, 0, stream>>>(G, boff);
    p1fill_kernel<<<NW1, 256, 0, stream>>>(src, dst, G, ebuf);
    p2build_kernel<<<NBUCK, 256, 0, stream>>>(ebuf, G, rowptr, srcsorted, dinv);

    const int GB = (NN + 63) / 64;   // 1563
    // layer 1
    gemm128m_kernel<false, float><<<GB, 256, 0, stream>>>(x, Wth, nullptr, dinv, A);
    agg128_kernel<<<NN / 4, 256, 0, stream>>>(A, rowptr, srcsorted, dinv, b1, Bh);
    bnstats_kernel<<<BNB, 256, 0, stream>>>(Bh, partial);
    bnfinal_kernel<<<1, 256, 0, stream>>>(partial, g1, be1, sc);
    // layer 2
    gemm128m_kernel<true, __half><<<GB, 256, 0, stream>>>(Bh, Wth + 16384, sc, dinv, A);
    agg128_kernel<<<NN / 4, 256, 0, stream>>>(A, rowptr, srcsorted, dinv, b2, Bh);
    bnstats_kernel<<<BNB, 256, 0, stream>>>(Bh, partial);
    bnfinal_kernel<<<1, 256, 0, stream>>>(partial, g2, be2, sc);
    // layer 3 (gemm40 writes padded 64-stride rows into A)
    gemm40_kernel<<<NN / 32, dim3(8, 32), 0, stream>>>(Bh, W3, sc, dinv, A);
    agg40_softmax_kernel<<<NN / 4, 256, 0, stream>>>(A, rowptr, srcsorted, dinv, b3, out);
}